// Round 4
// baseline (250.501 us; speedup 1.0000x reference)
//
#include <hip/hip_runtime.h>
#include <hip/hip_bf16.h>
#include <cstdint>

typedef __hip_bfloat16 bf16;
typedef short short8 __attribute__((ext_vector_type(8)));
typedef float f32x4 __attribute__((ext_vector_type(4)));

#define AS1C(p) ((const __attribute__((address_space(1))) void*)(p))
#define AS3(p)  ((__attribute__((address_space(3))) void*)(p))

__device__ __forceinline__ float b2f(short s) {
    union { unsigned u; float f; } c; c.u = ((unsigned)(unsigned short)s) << 16; return c.f;
}

// DPP cross-lane reduce within each 16-lane row.
template<int CTRL>
__device__ __forceinline__ float dppf(float x) {
    return __int_as_float(__builtin_amdgcn_update_dpp(
        0, __float_as_int(x), CTRL, 0xF, 0xF, true));
}
__device__ __forceinline__ float row_sum16(float x) {
    x += dppf<0xB1>(x);    // quad xor1
    x += dppf<0x4E>(x);    // quad xor2
    x += dppf<0x141>(x);   // row_half_mirror
    x += dppf<0x140>(x);   // row_mirror
    return x;
}

// ---------------------------------------------------------------------------
// Fused fp32 -> bf16 conversion for all three inputs in ONE launch.
// Segment layout (in float4 units): x | w_in | w_out.
// ---------------------------------------------------------------------------
#define N4_X  2097152   // 8192*1024/4
#define N4_WI  786432   // 3072*1024/4
#define N4_WO  262144   // 1024*1024/4
__global__ void cvt_all(const float* __restrict__ x, bf16* __restrict__ xb,
                        const float* __restrict__ wi, bf16* __restrict__ wib,
                        const float* __restrict__ wo, bf16* __restrict__ wob)
{
    int i = blockIdx.x * blockDim.x + threadIdx.x;
    const float* src; bf16* dst; int off;
    if (i < N4_X)                { src = x;  dst = xb;  off = i; }
    else if (i < N4_X + N4_WI)   { src = wi; dst = wib; off = i - N4_X; }
    else                         { src = wo; dst = wob; off = i - N4_X - N4_WI; }
    float4 v = ((const float4*)src)[off];
    __align__(8) bf16 t[4] = { __float2bfloat16(v.x), __float2bfloat16(v.y),
                               __float2bfloat16(v.z), __float2bfloat16(v.w) };
    ((uint2*)dst)[off] = *(const uint2*)t;
}

// ---------------------------------------------------------------------------
// C[M,N] = A[M,K] @ B[N,K]^T (+ bias). TM x 128 tile (TM = 128 or 256),
// TM/32 waves in (TM/64)x2 grid, BK=32, 16x16x32 bf16 MFMA, width-16
// global_load_lds staging, double-buffered LDS (1 barrier/iter), grid
// transposed (tile_m fast) for B-tile L2 reuse. Each wave: 4x4 16x16 accs.
// SPLIT_V: cols >= 2048 are written TRANSPOSED to vt[(b*16+h)*64+d][token].
// (R0-verified operating point: 706 TF on the 2-phase structure. 8-phase
//  256^2 rewrites regressed twice on this shape: 384 tiles @128KB LDS =
//  1 block/CU = 2 ragged rounds, and the ported schedule ran at ~53% of
//  m201's per-block rate. Keeping the verified structure.)
// ---------------------------------------------------------------------------
template<int TM, bool SPLIT_V, bool HAS_BIAS, typename OUT_T>
__global__ __launch_bounds__(TM * 2)
void gemm_bt(const bf16* __restrict__ A, int lda, const bf16* __restrict__ B,
             const float* __restrict__ bias, OUT_T* __restrict__ C, int ldc,
             bf16* __restrict__ vt, int M, int N, int K)
{
    constexpr int NWAVE = TM / 32;           // waves per block
    __shared__ __align__(16) bf16 As[2][TM * 32];
    __shared__ __align__(16) bf16 Bs[2][128 * 32];
    const int tid  = threadIdx.x;
    const int wave = tid >> 6, lane = tid & 63;
    const int wm = wave >> 1, wn = wave & 1;
    const int quad = lane >> 4, l15 = lane & 15;
    const int tile_m = blockIdx.x, tile_n = blockIdx.y;   // m fast: B-tile L2 reuse

    const bf16* Ap = A + (size_t)tile_m * TM * lda;
    const bf16* Bp = B + (size_t)tile_n * 128 * K;

    const int srow = lane >> 2;
    const int scol = (lane & 3) * 8;

    f32x4 acc[4][4];
    #pragma unroll
    for (int i = 0; i < 4; i++)
        #pragma unroll
        for (int j = 0; j < 4; j++) acc[i][j] = (f32x4){0.f, 0.f, 0.f, 0.f};

    #define GSTAGE(KI, BUF)                                                        \
        {   const int k0_ = (KI) * 32;                                             \
            _Pragma("unroll")                                                      \
            for (int cc = 0; cc < 2; cc++) {          /* A: TM/16 chunks */        \
                int c = wave + cc * NWAVE;                                         \
                const bf16* ga = Ap + (size_t)(c * 16 + srow) * lda + k0_ + scol;  \
                __builtin_amdgcn_global_load_lds(AS1C(ga),                         \
                    AS3(&As[BUF][c * 16 * 32]), 16, 0, 0);                         \
            }                                                                      \
            _Pragma("unroll")                                                      \
            for (int cc = 0; cc < 8 / NWAVE; cc++) {  /* B: 8 chunks */            \
                int c = wave + cc * NWAVE;                                         \
                const bf16* gb = Bp + (size_t)(c * 16 + srow) * K + k0_ + scol;    \
                __builtin_amdgcn_global_load_lds(AS1C(gb),                         \
                    AS3(&Bs[BUF][c * 16 * 32]), 16, 0, 0);                         \
            }                                                                      \
        }

    const int nk = K >> 5;
    GSTAGE(0, 0)
    for (int ki = 0; ki < nk; ki++) {
        __syncthreads();
        const int buf = ki & 1;
        if (ki + 1 < nk) GSTAGE(ki + 1, buf ^ 1)

        short8 af[4], bfr[4];
        #pragma unroll
        for (int mi = 0; mi < 4; mi++)
            af[mi] = *(const short8*)&As[buf][(wm * 64 + mi * 16 + l15) * 32 + quad * 8];
        #pragma unroll
        for (int ni = 0; ni < 4; ni++)
            bfr[ni] = *(const short8*)&Bs[buf][(wn * 64 + ni * 16 + l15) * 32 + quad * 8];
        #pragma unroll
        for (int mi = 0; mi < 4; mi++)
            #pragma unroll
            for (int ni = 0; ni < 4; ni++)
                acc[mi][ni] = __builtin_amdgcn_mfma_f32_16x16x32_bf16(
                    af[mi], bfr[ni], acc[mi][ni], 0, 0, 0);
    }
    #undef GSTAGE

    const bool vtile = SPLIT_V && (tile_n * 128 >= 2048);
    #pragma unroll
    for (int mi = 0; mi < 4; mi++) {
        #pragma unroll
        for (int ni = 0; ni < 4; ni++) {
            int coln = tile_n * 128 + wn * 64 + ni * 16 + l15;
            if (!vtile) {
                float bv = HAS_BIAS ? bias[coln] : 0.f;
                #pragma unroll
                for (int r = 0; r < 4; r++) {
                    int row = tile_m * TM + wm * 64 + mi * 16 + quad * 4 + r;
                    float v = acc[mi][ni][r] + bv;
                    if constexpr (__is_same(OUT_T, float))
                        C[(size_t)row * ldc + coln] = v;
                    else
                        C[(size_t)row * ldc + coln] = __float2bfloat16(v);
                }
            } else {
                int vcol = coln - 2048;                       // h*64 + d
                int row0 = tile_m * TM + wm * 64 + mi * 16 + quad * 4;
                int bb = row0 >> 11, n0 = row0 & 2047;
                __align__(8) bf16 t4[4];
                #pragma unroll
                for (int r = 0; r < 4; r++) t4[r] = __float2bfloat16(acc[mi][ni][r]);
                *(uint2*)&vt[((size_t)(bb * 1024 + vcol)) * 2048 + n0] = *(const uint2*)t4;
            }
        }
    }
}

// ---------------------------------------------------------------------------
// Causal flash attention. qkv: [8192,2048] = Q|K; vt: [4096,2048] = V^T.
// R4 delta: q-tile 128 -> 256 rows (8 waves, 512 threads). Same per-wave
// structure (32 q-rows each, 16x16 MFMA, XOR-swizzled K/V staging, Ps
// round-trip, setprio around MFMA). Halves K/V staging instructions and
// block count: 512 blocks @ 2/CU (68 KB LDS) = all-resident single round
// (vs 1024 @ 3/CU = 1.33 ragged rounds). launch_bounds(512,4) pins
// VGPR<=128 so 2 blocks/CU actually fit.
// ---------------------------------------------------------------------------
__global__ __launch_bounds__(512, 4)
void flash_attn(bf16* __restrict__ qkv, const bf16* __restrict__ vt)
{
    const int idx = blockIdx.x;
    const int qt  = 7 - (idx >> 6);          // 8 q-tiles of 256 rows; big first
    const int bh  = idx & 63;
    const int b   = bh >> 4, h = bh & 15;
    const int tid = threadIdx.x;
    const int wave = tid >> 6, lane = tid & 63;   // 8 waves
    const int quad = lane >> 4, l15 = lane & 15;

    __shared__ __align__(16) bf16 Ks[2][64 * 64];
    __shared__ __align__(16) bf16 Vs[2][64 * 64];
    __shared__ __align__(16) bf16 Ps[8][2][16][72];

    const int q0   = qt * 256;
    const int rowA = wave * 32;
    const size_t rs = 2048;

    const float QSC = 0.18033688011112042f;   // log2(e)/8
    short8 qa[2][2];
    #pragma unroll
    for (int mi = 0; mi < 2; mi++)
        #pragma unroll
        for (int kw = 0; kw < 2; kw++) {
            const bf16* qr = qkv + (size_t)(b * 2048 + q0 + rowA + mi * 16 + l15) * rs
                           + h * 64 + kw * 32 + quad * 8;
            short8 t = *(const short8*)qr;
            #pragma unroll
            for (int e = 0; e < 8; e++)
                t[e] = (short)__bfloat16_as_ushort(__float2bfloat16(b2f(t[e]) * QSC));
            qa[mi][kw] = t;
        }

    f32x4 o[2][4];
    #pragma unroll
    for (int mi = 0; mi < 2; mi++)
        #pragma unroll
        for (int nt = 0; nt < 4; nt++) o[mi][nt] = (f32x4){0.f, 0.f, 0.f, 0.f};
    float lsum[2][4] = {{0.f,0.f,0.f,0.f},{0.f,0.f,0.f,0.f}};

    const bf16* kbase = qkv + (size_t)(b * 2048) * rs + 1024 + h * 64;
    const bf16* vbase = vt + (size_t)(bh * 64) * 2048;

    const int srow8  = lane >> 3;
    const int schunk = (lane & 7) ^ srow8;

    // 8 waves x 8 rows = 64-row K and V tiles, one global_load_lds each.
    #define STAGE(J, BUF)                                                          \
        {   const int jj = (J);                                                    \
            int rr_ = wave * 8 + srow8;                                            \
            const bf16* gk = kbase + (size_t)(jj * 64 + rr_) * rs + schunk * 8;    \
            __builtin_amdgcn_global_load_lds(AS1C(gk),                             \
                AS3(&Ks[BUF][(wave * 8) * 64]), 16, 0, 0);                         \
            const bf16* gv = vbase + (size_t)rr_ * 2048 + jj * 64 + schunk * 8;    \
            __builtin_amdgcn_global_load_lds(AS1C(gv),                             \
                AS3(&Vs[BUF][(wave * 8) * 64]), 16, 0, 0);                         \
        }

    STAGE(0, 0)
    const int jmax = 4 * qt + 3;
    for (int j = 0; j <= jmax; j++) {
        __syncthreads();
        const int buf = j & 1;
        if (j < jmax) STAGE(j + 1, buf ^ 1)

        if (j * 64 > q0 + rowA + 31) continue;

        f32x4 s[2][4];
        #pragma unroll
        for (int mi = 0; mi < 2; mi++)
            #pragma unroll
            for (int tc = 0; tc < 4; tc++) s[mi][tc] = (f32x4){0.f,0.f,0.f,0.f};
        #pragma unroll
        for (int kw = 0; kw < 2; kw++) {
            short8 kb[4];
            #pragma unroll
            for (int tc = 0; tc < 4; tc++)
                kb[tc] = *(const short8*)&Ks[buf][(tc * 16 + l15) * 64 +
                         (((kw * 4 + quad) ^ (l15 & 7)) * 8)];
            __builtin_amdgcn_s_setprio(1);
            #pragma unroll
            for (int mi = 0; mi < 2; mi++)
                #pragma unroll
                for (int tc = 0; tc < 4; tc++)
                    s[mi][tc] = __builtin_amdgcn_mfma_f32_16x16x32_bf16(
                        qa[mi][kw], kb[tc], s[mi][tc], 0, 0, 0);
            __builtin_amdgcn_s_setprio(0);
        }
        if (j * 64 + 63 > q0 + rowA) {
            #pragma unroll
            for (int mi = 0; mi < 2; mi++)
                #pragma unroll
                for (int tc = 0; tc < 4; tc++)
                    #pragma unroll
                    for (int rr = 0; rr < 4; rr++)
                        if (j * 64 + tc * 16 + l15 >
                            q0 + rowA + mi * 16 + quad * 4 + rr)
                            s[mi][tc][rr] = -INFINITY;
        }
        #pragma unroll
        for (int mi = 0; mi < 2; mi++) {
            #pragma unroll
            for (int tc = 0; tc < 4; tc++)
                #pragma unroll
                for (int rr = 0; rr < 4; rr++)
                    s[mi][tc][rr] = __builtin_amdgcn_exp2f(s[mi][tc][rr]);
            #pragma unroll
            for (int rr = 0; rr < 4; rr++)
                lsum[mi][rr] += (s[mi][0][rr] + s[mi][1][rr]) +
                                (s[mi][2][rr] + s[mi][3][rr]);
        }
        #pragma unroll
        for (int mi = 0; mi < 2; mi++)
            #pragma unroll
            for (int tc = 0; tc < 4; tc++)
                #pragma unroll
                for (int rr = 0; rr < 4; rr++)
                    Ps[wave][mi][quad * 4 + rr][tc * 16 + l15] =
                        __float2bfloat16(s[mi][tc][rr]);
        #pragma unroll
        for (int kw = 0; kw < 2; kw++) {
            short8 vb[4];
            #pragma unroll
            for (int nt = 0; nt < 4; nt++)
                vb[nt] = *(const short8*)&Vs[buf][(nt * 16 + l15) * 64 +
                         (((kw * 4 + quad) ^ (l15 & 7)) * 8)];
            short8 pa[2];
            #pragma unroll
            for (int mi = 0; mi < 2; mi++)
                pa[mi] = *(const short8*)&Ps[wave][mi][l15][kw * 32 + quad * 8];
            __builtin_amdgcn_s_setprio(1);
            #pragma unroll
            for (int mi = 0; mi < 2; mi++)
                #pragma unroll
                for (int nt = 0; nt < 4; nt++)
                    o[mi][nt] = __builtin_amdgcn_mfma_f32_16x16x32_bf16(
                        pa[mi], vb[nt], o[mi][nt], 0, 0, 0);
            __builtin_amdgcn_s_setprio(0);
        }
    }
    #undef STAGE

    #pragma unroll
    for (int mi = 0; mi < 2; mi++)
        #pragma unroll
        for (int rr = 0; rr < 4; rr++) {
            float inv = 1.f / row_sum16(lsum[mi][rr]);
            int row = b * 2048 + q0 + rowA + mi * 16 + quad * 4 + rr;
            #pragma unroll
            for (int nt = 0; nt < 4; nt++) {
                int col = h * 64 + nt * 16 + l15;
                qkv[(size_t)row * rs + col] = __float2bfloat16(o[mi][nt][rr] * inv);
            }
        }
}

// ---------------------------------------------------------------------------
extern "C" void kernel_launch(void* const* d_in, const int* in_sizes, int n_in,
                              void* d_out, int out_size, void* d_ws, size_t ws_size,
                              hipStream_t stream)
{
    const float* x     = (const float*)d_in[0];  // [4,2048,1024] fp32
    const float* w_in  = (const float*)d_in[1];  // [3072,1024]   fp32
    const float* w_out = (const float*)d_in[2];  // [1024,1024]   fp32
    const float* b_out = (const float*)d_in[3];  // [1024]        fp32
    float* out = (float*)d_out;                  // [4,2048,1024] fp32

    // ws: qkv(Q|K) 33.5MB | vt 16.8MB | xb 16.8MB | wib 6.3MB | wob 2.1MB
    bf16* qkv = (bf16*)d_ws;                     // [8192, 2048]
    bf16* vt  = qkv + (size_t)8192 * 2048;       // [4096, 2048]
    bf16* xb  = vt  + (size_t)4096 * 2048;       // [8192, 1024]
    bf16* wib = xb  + (size_t)8192 * 1024;       // [3072, 1024]
    bf16* wob = wib + (size_t)3072 * 1024;       // [1024, 1024]

    // 0) one fused conversion launch
    cvt_all<<<(N4_X + N4_WI + N4_WO) / 256, 256, 0, stream>>>(
        x, xb, w_in, wib, w_out, wob);

    // 1) qkv = x @ w_in^T  (Q,K -> qkv stride 2048; V -> vt transposed)
    //    256x128 tile, 512 threads: staging+barrier cost per MFMA halves
    gemm_bt<256, true, false, bf16><<<dim3(8192 / 256, 3072 / 128), 512, 0, stream>>>(
        xb, 1024, wib, nullptr, qkv, 2048, vt, 8192, 3072, 1024);
    // 2) causal flash attention (output into Q columns of qkv)
    //    512 blocks x 512 threads: 2 blocks/CU, single dispatch round
    flash_attn<<<512, 512, 0, stream>>>(qkv, vt);
    // 3) out = attn_out @ w_out^T + b_out  (128x128: keeps 512 blocks, no tail)
    gemm_bt<128, false, true, float><<<dim3(8192 / 128, 1024 / 128), 256, 0, stream>>>(
        qkv, 2048, wob, b_out, out, 1024, nullptr, 8192, 1024, 1024);
}

// Round 5
// 239.410 us; speedup vs baseline: 1.0463x; 1.0463x over previous
//
#include <hip/hip_runtime.h>
#include <hip/hip_bf16.h>
#include <cstdint>

typedef __hip_bfloat16 bf16;
typedef short short8 __attribute__((ext_vector_type(8)));
typedef float f32x4 __attribute__((ext_vector_type(4)));

#define AS1C(p) ((const __attribute__((address_space(1))) void*)(p))
#define AS3(p)  ((__attribute__((address_space(3))) void*)(p))

__device__ __forceinline__ float b2f(short s) {
    union { unsigned u; float f; } c; c.u = ((unsigned)(unsigned short)s) << 16; return c.f;
}

// DPP cross-lane reduce within each 16-lane row.
template<int CTRL>
__device__ __forceinline__ float dppf(float x) {
    return __int_as_float(__builtin_amdgcn_update_dpp(
        0, __float_as_int(x), CTRL, 0xF, 0xF, true));
}
__device__ __forceinline__ float row_sum16(float x) {
    x += dppf<0xB1>(x);    // quad xor1
    x += dppf<0x4E>(x);    // quad xor2
    x += dppf<0x141>(x);   // row_half_mirror
    x += dppf<0x140>(x);   // row_mirror
    return x;
}

// ---------------------------------------------------------------------------
// Fused fp32 -> bf16 conversion for all three inputs in ONE launch.
// Segment layout (in float4 units): x | w_in | w_out.
// ---------------------------------------------------------------------------
#define N4_X  2097152   // 8192*1024/4
#define N4_WI  786432   // 3072*1024/4
#define N4_WO  262144   // 1024*1024/4
__global__ void cvt_all(const float* __restrict__ x, bf16* __restrict__ xb,
                        const float* __restrict__ wi, bf16* __restrict__ wib,
                        const float* __restrict__ wo, bf16* __restrict__ wob)
{
    int i = blockIdx.x * blockDim.x + threadIdx.x;
    const float* src; bf16* dst; int off;
    if (i < N4_X)                { src = x;  dst = xb;  off = i; }
    else if (i < N4_X + N4_WI)   { src = wi; dst = wib; off = i - N4_X; }
    else                         { src = wo; dst = wob; off = i - N4_X - N4_WI; }
    float4 v = ((const float4*)src)[off];
    __align__(8) bf16 t[4] = { __float2bfloat16(v.x), __float2bfloat16(v.y),
                               __float2bfloat16(v.z), __float2bfloat16(v.w) };
    ((uint2*)dst)[off] = *(const uint2*)t;
}

// ---------------------------------------------------------------------------
// C[M,N] = A[M,K] @ B[N,K]^T (+ bias). TM x 128 tile (TM = 128 or 256),
// TM/32 waves in (TM/64)x2 grid, BK=32, 16x16x32 bf16 MFMA, width-16
// global_load_lds staging, double-buffered LDS (1 barrier/iter), grid
// transposed (tile_m fast) for B-tile L2 reuse. Each wave: 4x4 16x16 accs.
// SPLIT_V: cols >= 2048 are written TRANSPOSED to vt[(b*16+h)*64+d][token].
// (R0-verified operating point: 706 TF on the 2-phase structure. 8-phase
//  256^2 rewrites regressed twice on this shape: 384 tiles @128KB LDS =
//  1 block/CU = 2 ragged rounds, and the ported schedule ran at ~53% of
//  m201's per-block rate. Keeping the verified structure.)
// ---------------------------------------------------------------------------
template<int TM, bool SPLIT_V, bool HAS_BIAS, typename OUT_T>
__global__ __launch_bounds__(TM * 2)
void gemm_bt(const bf16* __restrict__ A, int lda, const bf16* __restrict__ B,
             const float* __restrict__ bias, OUT_T* __restrict__ C, int ldc,
             bf16* __restrict__ vt, int M, int N, int K)
{
    constexpr int NWAVE = TM / 32;           // waves per block
    __shared__ __align__(16) bf16 As[2][TM * 32];
    __shared__ __align__(16) bf16 Bs[2][128 * 32];
    const int tid  = threadIdx.x;
    const int wave = tid >> 6, lane = tid & 63;
    const int wm = wave >> 1, wn = wave & 1;
    const int quad = lane >> 4, l15 = lane & 15;
    const int tile_m = blockIdx.x, tile_n = blockIdx.y;   // m fast: B-tile L2 reuse

    const bf16* Ap = A + (size_t)tile_m * TM * lda;
    const bf16* Bp = B + (size_t)tile_n * 128 * K;

    const int srow = lane >> 2;
    const int scol = (lane & 3) * 8;

    f32x4 acc[4][4];
    #pragma unroll
    for (int i = 0; i < 4; i++)
        #pragma unroll
        for (int j = 0; j < 4; j++) acc[i][j] = (f32x4){0.f, 0.f, 0.f, 0.f};

    #define GSTAGE(KI, BUF)                                                        \
        {   const int k0_ = (KI) * 32;                                             \
            _Pragma("unroll")                                                      \
            for (int cc = 0; cc < 2; cc++) {          /* A: TM/16 chunks */        \
                int c = wave + cc * NWAVE;                                         \
                const bf16* ga = Ap + (size_t)(c * 16 + srow) * lda + k0_ + scol;  \
                __builtin_amdgcn_global_load_lds(AS1C(ga),                         \
                    AS3(&As[BUF][c * 16 * 32]), 16, 0, 0);                         \
            }                                                                      \
            _Pragma("unroll")                                                      \
            for (int cc = 0; cc < 8 / NWAVE; cc++) {  /* B: 8 chunks */            \
                int c = wave + cc * NWAVE;                                         \
                const bf16* gb = Bp + (size_t)(c * 16 + srow) * K + k0_ + scol;    \
                __builtin_amdgcn_global_load_lds(AS1C(gb),                         \
                    AS3(&Bs[BUF][c * 16 * 32]), 16, 0, 0);                         \
            }                                                                      \
        }

    const int nk = K >> 5;
    GSTAGE(0, 0)
    for (int ki = 0; ki < nk; ki++) {
        __syncthreads();
        const int buf = ki & 1;
        if (ki + 1 < nk) GSTAGE(ki + 1, buf ^ 1)

        short8 af[4], bfr[4];
        #pragma unroll
        for (int mi = 0; mi < 4; mi++)
            af[mi] = *(const short8*)&As[buf][(wm * 64 + mi * 16 + l15) * 32 + quad * 8];
        #pragma unroll
        for (int ni = 0; ni < 4; ni++)
            bfr[ni] = *(const short8*)&Bs[buf][(wn * 64 + ni * 16 + l15) * 32 + quad * 8];
        #pragma unroll
        for (int mi = 0; mi < 4; mi++)
            #pragma unroll
            for (int ni = 0; ni < 4; ni++)
                acc[mi][ni] = __builtin_amdgcn_mfma_f32_16x16x32_bf16(
                    af[mi], bfr[ni], acc[mi][ni], 0, 0, 0);
    }
    #undef GSTAGE

    const bool vtile = SPLIT_V && (tile_n * 128 >= 2048);
    #pragma unroll
    for (int mi = 0; mi < 4; mi++) {
        #pragma unroll
        for (int ni = 0; ni < 4; ni++) {
            int coln = tile_n * 128 + wn * 64 + ni * 16 + l15;
            if (!vtile) {
                float bv = HAS_BIAS ? bias[coln] : 0.f;
                #pragma unroll
                for (int r = 0; r < 4; r++) {
                    int row = tile_m * TM + wm * 64 + mi * 16 + quad * 4 + r;
                    float v = acc[mi][ni][r] + bv;
                    if constexpr (__is_same(OUT_T, float))
                        C[(size_t)row * ldc + coln] = v;
                    else
                        C[(size_t)row * ldc + coln] = __float2bfloat16(v);
                }
            } else {
                int vcol = coln - 2048;                       // h*64 + d
                int row0 = tile_m * TM + wm * 64 + mi * 16 + quad * 4;
                int bb = row0 >> 11, n0 = row0 & 2047;
                __align__(8) bf16 t4[4];
                #pragma unroll
                for (int r = 0; r < 4; r++) t4[r] = __float2bfloat16(acc[mi][ni][r]);
                *(uint2*)&vt[((size_t)(bb * 1024 + vcol)) * 2048 + n0] = *(const uint2*)t4;
            }
        }
    }
}

// ---------------------------------------------------------------------------
// Causal flash attention (R3-exact, the 241.4 us operating point).
// qkv: [8192,2048] = Q|K; vt: [4096,2048] = V^T. Block = 128 q-rows x
// (head,batch); wave w owns q-rows w*32..+31. K/V 64x64 tiles double-
// buffered via global_load_lds with XOR swizzle; 1 barrier/iter.
// Unstabilized softmax with log2(e)/8 folded into Q. Output overwrites
// Q cols. setprio(1) around MFMA clusters (T5, m191 regime: +4-7%).
// (R4's 256-row q-tile regressed: launch_bounds(512,4) VGPR cap + coarse
//  512-block grid pairing long/short blocks -> worse makespan. Reverted.)
// ---------------------------------------------------------------------------
__global__ __launch_bounds__(256, 3)
void flash_attn(bf16* __restrict__ qkv, const bf16* __restrict__ vt)
{
    const int idx = blockIdx.x;
    const int qt  = 15 - (idx >> 6);
    const int bh  = idx & 63;
    const int b   = bh >> 4, h = bh & 15;
    const int tid = threadIdx.x;
    const int wave = tid >> 6, lane = tid & 63;
    const int quad = lane >> 4, l15 = lane & 15;

    __shared__ __align__(16) bf16 Ks[2][64 * 64];
    __shared__ __align__(16) bf16 Vs[2][64 * 64];
    __shared__ __align__(16) bf16 Ps[4][2][16][72];

    const int q0   = qt * 128;
    const int rowA = wave * 32;
    const size_t rs = 2048;

    const float QSC = 0.18033688011112042f;   // log2(e)/8
    short8 qa[2][2];
    #pragma unroll
    for (int mi = 0; mi < 2; mi++)
        #pragma unroll
        for (int kw = 0; kw < 2; kw++) {
            const bf16* qr = qkv + (size_t)(b * 2048 + q0 + rowA + mi * 16 + l15) * rs
                           + h * 64 + kw * 32 + quad * 8;
            short8 t = *(const short8*)qr;
            #pragma unroll
            for (int e = 0; e < 8; e++)
                t[e] = (short)__bfloat16_as_ushort(__float2bfloat16(b2f(t[e]) * QSC));
            qa[mi][kw] = t;
        }

    f32x4 o[2][4];
    #pragma unroll
    for (int mi = 0; mi < 2; mi++)
        #pragma unroll
        for (int nt = 0; nt < 4; nt++) o[mi][nt] = (f32x4){0.f, 0.f, 0.f, 0.f};
    float lsum[2][4] = {{0.f,0.f,0.f,0.f},{0.f,0.f,0.f,0.f}};

    const bf16* kbase = qkv + (size_t)(b * 2048) * rs + 1024 + h * 64;
    const bf16* vbase = vt + (size_t)(bh * 64) * 2048;

    const int srow8  = lane >> 3;
    const int schunk = (lane & 7) ^ srow8;

    #define STAGE(J, BUF)                                                          \
        {   const int jj = (J);                                                    \
            _Pragma("unroll")                                                      \
            for (int i = 0; i < 2; i++) {                                          \
                int rr_ = wave * 16 + i * 8 + srow8;                               \
                const bf16* gk = kbase + (size_t)(jj * 64 + rr_) * rs + schunk * 8;\
                __builtin_amdgcn_global_load_lds(AS1C(gk),                         \
                    AS3(&Ks[BUF][(wave * 16 + i * 8) * 64]), 16, 0, 0);            \
                const bf16* gv = vbase + (size_t)rr_ * 2048 + jj * 64 + schunk * 8;\
                __builtin_amdgcn_global_load_lds(AS1C(gv),                         \
                    AS3(&Vs[BUF][(wave * 16 + i * 8) * 64]), 16, 0, 0);            \
            }                                                                      \
        }

    STAGE(0, 0)
    const int jmax = 2 * qt + 1;
    for (int j = 0; j <= jmax; j++) {
        __syncthreads();
        const int buf = j & 1;
        if (j < jmax) STAGE(j + 1, buf ^ 1)

        if (j * 64 > q0 + rowA + 31) continue;

        f32x4 s[2][4];
        #pragma unroll
        for (int mi = 0; mi < 2; mi++)
            #pragma unroll
            for (int tc = 0; tc < 4; tc++) s[mi][tc] = (f32x4){0.f,0.f,0.f,0.f};
        #pragma unroll
        for (int kw = 0; kw < 2; kw++) {
            short8 kb[4];
            #pragma unroll
            for (int tc = 0; tc < 4; tc++)
                kb[tc] = *(const short8*)&Ks[buf][(tc * 16 + l15) * 64 +
                         (((kw * 4 + quad) ^ (l15 & 7)) * 8)];
            __builtin_amdgcn_s_setprio(1);
            #pragma unroll
            for (int mi = 0; mi < 2; mi++)
                #pragma unroll
                for (int tc = 0; tc < 4; tc++)
                    s[mi][tc] = __builtin_amdgcn_mfma_f32_16x16x32_bf16(
                        qa[mi][kw], kb[tc], s[mi][tc], 0, 0, 0);
            __builtin_amdgcn_s_setprio(0);
        }
        if (j * 64 + 63 > q0 + rowA) {
            #pragma unroll
            for (int mi = 0; mi < 2; mi++)
                #pragma unroll
                for (int tc = 0; tc < 4; tc++)
                    #pragma unroll
                    for (int rr = 0; rr < 4; rr++)
                        if (j * 64 + tc * 16 + l15 >
                            q0 + rowA + mi * 16 + quad * 4 + rr)
                            s[mi][tc][rr] = -INFINITY;
        }
        #pragma unroll
        for (int mi = 0; mi < 2; mi++) {
            #pragma unroll
            for (int tc = 0; tc < 4; tc++)
                #pragma unroll
                for (int rr = 0; rr < 4; rr++)
                    s[mi][tc][rr] = __builtin_amdgcn_exp2f(s[mi][tc][rr]);
            #pragma unroll
            for (int rr = 0; rr < 4; rr++)
                lsum[mi][rr] += (s[mi][0][rr] + s[mi][1][rr]) +
                                (s[mi][2][rr] + s[mi][3][rr]);
        }
        #pragma unroll
        for (int mi = 0; mi < 2; mi++)
            #pragma unroll
            for (int tc = 0; tc < 4; tc++)
                #pragma unroll
                for (int rr = 0; rr < 4; rr++)
                    Ps[wave][mi][quad * 4 + rr][tc * 16 + l15] =
                        __float2bfloat16(s[mi][tc][rr]);
        #pragma unroll
        for (int kw = 0; kw < 2; kw++) {
            short8 vb[4];
            #pragma unroll
            for (int nt = 0; nt < 4; nt++)
                vb[nt] = *(const short8*)&Vs[buf][(nt * 16 + l15) * 64 +
                         (((kw * 4 + quad) ^ (l15 & 7)) * 8)];
            short8 pa[2];
            #pragma unroll
            for (int mi = 0; mi < 2; mi++)
                pa[mi] = *(const short8*)&Ps[wave][mi][l15][kw * 32 + quad * 8];
            __builtin_amdgcn_s_setprio(1);
            #pragma unroll
            for (int mi = 0; mi < 2; mi++)
                #pragma unroll
                for (int nt = 0; nt < 4; nt++)
                    o[mi][nt] = __builtin_amdgcn_mfma_f32_16x16x32_bf16(
                        pa[mi], vb[nt], o[mi][nt], 0, 0, 0);
            __builtin_amdgcn_s_setprio(0);
        }
    }
    #undef STAGE

    #pragma unroll
    for (int mi = 0; mi < 2; mi++)
        #pragma unroll
        for (int rr = 0; rr < 4; rr++) {
            float inv = 1.f / row_sum16(lsum[mi][rr]);
            int row = b * 2048 + q0 + rowA + mi * 16 + quad * 4 + rr;
            #pragma unroll
            for (int nt = 0; nt < 4; nt++) {
                int col = h * 64 + nt * 16 + l15;
                qkv[(size_t)row * rs + col] = __float2bfloat16(o[mi][nt][rr] * inv);
            }
        }
}

// ---------------------------------------------------------------------------
extern "C" void kernel_launch(void* const* d_in, const int* in_sizes, int n_in,
                              void* d_out, int out_size, void* d_ws, size_t ws_size,
                              hipStream_t stream)
{
    const float* x     = (const float*)d_in[0];  // [4,2048,1024] fp32
    const float* w_in  = (const float*)d_in[1];  // [3072,1024]   fp32
    const float* w_out = (const float*)d_in[2];  // [1024,1024]   fp32
    const float* b_out = (const float*)d_in[3];  // [1024]        fp32
    float* out = (float*)d_out;                  // [4,2048,1024] fp32

    // ws: qkv(Q|K) 33.5MB | vt 16.8MB | xb 16.8MB | wib 6.3MB | wob 2.1MB
    bf16* qkv = (bf16*)d_ws;                     // [8192, 2048]
    bf16* vt  = qkv + (size_t)8192 * 2048;       // [4096, 2048]
    bf16* xb  = vt  + (size_t)4096 * 2048;       // [8192, 1024]
    bf16* wib = xb  + (size_t)8192 * 1024;       // [3072, 1024]
    bf16* wob = wib + (size_t)3072 * 1024;       // [1024, 1024]

    // 0) one fused conversion launch
    cvt_all<<<(N4_X + N4_WI + N4_WO) / 256, 256, 0, stream>>>(
        x, xb, w_in, wib, w_out, wob);

    // 1) qkv = x @ w_in^T  (Q,K -> qkv stride 2048; V -> vt transposed)
    //    256x128 tile, 512 threads: staging+barrier cost per MFMA halves
    gemm_bt<256, true, false, bf16><<<dim3(8192 / 256, 3072 / 128), 512, 0, stream>>>(
        xb, 1024, wib, nullptr, qkv, 2048, vt, 8192, 3072, 1024);
    // 2) causal flash attention (output into Q columns of qkv)
    flash_attn<<<1024, 256, 0, stream>>>(qkv, vt);
    // 3) out = attn_out @ w_out^T + b_out
    //    R5: TM=256 (gemm1's verified 706 TF config; same per-block work).
    //    grid 32x8 = 256 blocks exact, 1/CU single round, no tail.
    gemm_bt<256, false, true, float><<<dim3(8192 / 256, 1024 / 128), 512, 0, stream>>>(
        qkv, 2048, wob, b_out, out, 1024, nullptr, 8192, 1024, 1024);
}

// Round 6
// 237.150 us; speedup vs baseline: 1.0563x; 1.0095x over previous
//
#include <hip/hip_runtime.h>
#include <hip/hip_bf16.h>
#include <cstdint>

typedef __hip_bfloat16 bf16;
typedef short short8 __attribute__((ext_vector_type(8)));
typedef float f32x4 __attribute__((ext_vector_type(4)));

#define AS1C(p) ((const __attribute__((address_space(1))) void*)(p))
#define AS3(p)  ((__attribute__((address_space(3))) void*)(p))

__device__ __forceinline__ float b2f(short s) {
    union { unsigned u; float f; } c; c.u = ((unsigned)(unsigned short)s) << 16; return c.f;
}

// ---------------------------------------------------------------------------
// Fused fp32 -> bf16 conversion for all three inputs in ONE launch.
// Segment layout (in float4 units): x | w_in | w_out.
// ---------------------------------------------------------------------------
#define N4_X  2097152   // 8192*1024/4
#define N4_WI  786432   // 3072*1024/4
#define N4_WO  262144   // 1024*1024/4
__global__ void cvt_all(const float* __restrict__ x, bf16* __restrict__ xb,
                        const float* __restrict__ wi, bf16* __restrict__ wib,
                        const float* __restrict__ wo, bf16* __restrict__ wob)
{
    int i = blockIdx.x * blockDim.x + threadIdx.x;
    const float* src; bf16* dst; int off;
    if (i < N4_X)                { src = x;  dst = xb;  off = i; }
    else if (i < N4_X + N4_WI)   { src = wi; dst = wib; off = i - N4_X; }
    else                         { src = wo; dst = wob; off = i - N4_X - N4_WI; }
    float4 v = ((const float4*)src)[off];
    __align__(8) bf16 t[4] = { __float2bfloat16(v.x), __float2bfloat16(v.y),
                               __float2bfloat16(v.z), __float2bfloat16(v.w) };
    ((uint2*)dst)[off] = *(const uint2*)t;
}

// ---------------------------------------------------------------------------
// C[M,N] = A[M,K] @ B[N,K]^T (+ bias). TM x 128 tile (TM = 128 or 256),
// TM/32 waves in (TM/64)x2 grid, BK=32, 16x16x32 bf16 MFMA, width-16
// global_load_lds staging, double-buffered LDS (1 barrier/iter), grid
// transposed (tile_m fast) for B-tile L2 reuse. Each wave: 4x4 16x16 accs.
// SPLIT_V: cols >= 2048 are written TRANSPOSED to vt[(b*16+h)*64+d][token].
// (R0-verified operating point: 706 TF on the 2-phase structure. 8-phase
//  256^2 rewrites regressed twice on this shape: 384 tiles @128KB LDS =
//  1 block/CU = 2 ragged rounds, and the ported schedule ran at ~53% of
//  m201's per-block rate. Keeping the verified structure.)
// ---------------------------------------------------------------------------
template<int TM, bool SPLIT_V, bool HAS_BIAS, typename OUT_T>
__global__ __launch_bounds__(TM * 2)
void gemm_bt(const bf16* __restrict__ A, int lda, const bf16* __restrict__ B,
             const float* __restrict__ bias, OUT_T* __restrict__ C, int ldc,
             bf16* __restrict__ vt, int M, int N, int K)
{
    constexpr int NWAVE = TM / 32;           // waves per block
    __shared__ __align__(16) bf16 As[2][TM * 32];
    __shared__ __align__(16) bf16 Bs[2][128 * 32];
    const int tid  = threadIdx.x;
    const int wave = tid >> 6, lane = tid & 63;
    const int wm = wave >> 1, wn = wave & 1;
    const int quad = lane >> 4, l15 = lane & 15;
    const int tile_m = blockIdx.x, tile_n = blockIdx.y;   // m fast: B-tile L2 reuse

    const bf16* Ap = A + (size_t)tile_m * TM * lda;
    const bf16* Bp = B + (size_t)tile_n * 128 * K;

    const int srow = lane >> 2;
    const int scol = (lane & 3) * 8;

    f32x4 acc[4][4];
    #pragma unroll
    for (int i = 0; i < 4; i++)
        #pragma unroll
        for (int j = 0; j < 4; j++) acc[i][j] = (f32x4){0.f, 0.f, 0.f, 0.f};

    #define GSTAGE(KI, BUF)                                                        \
        {   const int k0_ = (KI) * 32;                                             \
            _Pragma("unroll")                                                      \
            for (int cc = 0; cc < 2; cc++) {          /* A: TM/16 chunks */        \
                int c = wave + cc * NWAVE;                                         \
                const bf16* ga = Ap + (size_t)(c * 16 + srow) * lda + k0_ + scol;  \
                __builtin_amdgcn_global_load_lds(AS1C(ga),                         \
                    AS3(&As[BUF][c * 16 * 32]), 16, 0, 0);                         \
            }                                                                      \
            _Pragma("unroll")                                                      \
            for (int cc = 0; cc < 8 / NWAVE; cc++) {  /* B: 8 chunks */            \
                int c = wave + cc * NWAVE;                                         \
                const bf16* gb = Bp + (size_t)(c * 16 + srow) * K + k0_ + scol;    \
                __builtin_amdgcn_global_load_lds(AS1C(gb),                         \
                    AS3(&Bs[BUF][c * 16 * 32]), 16, 0, 0);                         \
            }                                                                      \
        }

    const int nk = K >> 5;
    GSTAGE(0, 0)
    for (int ki = 0; ki < nk; ki++) {
        __syncthreads();
        const int buf = ki & 1;
        if (ki + 1 < nk) GSTAGE(ki + 1, buf ^ 1)

        short8 af[4], bfr[4];
        #pragma unroll
        for (int mi = 0; mi < 4; mi++)
            af[mi] = *(const short8*)&As[buf][(wm * 64 + mi * 16 + l15) * 32 + quad * 8];
        #pragma unroll
        for (int ni = 0; ni < 4; ni++)
            bfr[ni] = *(const short8*)&Bs[buf][(wn * 64 + ni * 16 + l15) * 32 + quad * 8];
        #pragma unroll
        for (int mi = 0; mi < 4; mi++)
            #pragma unroll
            for (int ni = 0; ni < 4; ni++)
                acc[mi][ni] = __builtin_amdgcn_mfma_f32_16x16x32_bf16(
                    af[mi], bfr[ni], acc[mi][ni], 0, 0, 0);
    }
    #undef GSTAGE

    const bool vtile = SPLIT_V && (tile_n * 128 >= 2048);
    #pragma unroll
    for (int mi = 0; mi < 4; mi++) {
        #pragma unroll
        for (int ni = 0; ni < 4; ni++) {
            int coln = tile_n * 128 + wn * 64 + ni * 16 + l15;
            if (!vtile) {
                float bv = HAS_BIAS ? bias[coln] : 0.f;
                #pragma unroll
                for (int r = 0; r < 4; r++) {
                    int row = tile_m * TM + wm * 64 + mi * 16 + quad * 4 + r;
                    float v = acc[mi][ni][r] + bv;
                    if constexpr (__is_same(OUT_T, float))
                        C[(size_t)row * ldc + coln] = v;
                    else
                        C[(size_t)row * ldc + coln] = __float2bfloat16(v);
                }
            } else {
                int vcol = coln - 2048;                       // h*64 + d
                int row0 = tile_m * TM + wm * 64 + mi * 16 + quad * 4;
                int bb = row0 >> 11, n0 = row0 & 2047;
                __align__(8) bf16 t4[4];
                #pragma unroll
                for (int r = 0; r < 4; r++) t4[r] = __float2bfloat16(acc[mi][ni][r]);
                *(uint2*)&vt[((size_t)(bb * 1024 + vcol)) * 2048 + n0] = *(const uint2*)t4;
            }
        }
    }
}

// ---------------------------------------------------------------------------
// Causal flash attention. qkv: [8192,2048] = Q|K; vt: [4096,2048] = V^T.
// Block = 128 q-rows x (head,batch); wave w owns q-rows w*32..+31.
// K/V 64x64 tiles double-buffered via global_load_lds with XOR swizzle;
// 1 barrier/iter. Unstabilized softmax with log2(e)/8 folded into Q.
// Output overwrites Q cols. setprio(1) around MFMA clusters (T5/m191).
// R6 delta: SWAPPED QK^T — s = mfma(K,Q) (A/B frags share the same lane
// mapping, so the swap is operand order only). Output is P[k][q=l15]:
// rr now runs along k, so the Ps store packs rr 0..3 into ONE b64 write:
// 8 x ds_write_b64 replace 32 x ds_write_b16 per iter. The PV-side read
// (pa = Ps[mi][l15][kw*32+quad*8], row=q=l15) is UNCHANGED. Mask predicate
// re-indexed to the new mapping (same k>q condition); lsum is one scalar
// per mi (row total via shfl_xor 16/32); inv fetched per (quad,rr) with 8
// epilogue shuffles.
// ---------------------------------------------------------------------------
__global__ __launch_bounds__(256, 3)
void flash_attn(bf16* __restrict__ qkv, const bf16* __restrict__ vt)
{
    const int idx = blockIdx.x;
    const int qt  = 15 - (idx >> 6);
    const int bh  = idx & 63;
    const int b   = bh >> 4, h = bh & 15;
    const int tid = threadIdx.x;
    const int wave = tid >> 6, lane = tid & 63;
    const int quad = lane >> 4, l15 = lane & 15;

    __shared__ __align__(16) bf16 Ks[2][64 * 64];
    __shared__ __align__(16) bf16 Vs[2][64 * 64];
    __shared__ __align__(16) bf16 Ps[4][2][16][72];

    const int q0   = qt * 128;
    const int rowA = wave * 32;
    const size_t rs = 2048;

    const float QSC = 0.18033688011112042f;   // log2(e)/8
    short8 qa[2][2];
    #pragma unroll
    for (int mi = 0; mi < 2; mi++)
        #pragma unroll
        for (int kw = 0; kw < 2; kw++) {
            const bf16* qr = qkv + (size_t)(b * 2048 + q0 + rowA + mi * 16 + l15) * rs
                           + h * 64 + kw * 32 + quad * 8;
            short8 t = *(const short8*)qr;
            #pragma unroll
            for (int e = 0; e < 8; e++)
                t[e] = (short)__bfloat16_as_ushort(__float2bfloat16(b2f(t[e]) * QSC));
            qa[mi][kw] = t;
        }

    f32x4 o[2][4];
    #pragma unroll
    for (int mi = 0; mi < 2; mi++)
        #pragma unroll
        for (int nt = 0; nt < 4; nt++) o[mi][nt] = (f32x4){0.f, 0.f, 0.f, 0.f};
    float lsum[2] = {0.f, 0.f};   // per-thread partial of q-row l15 (per mi)

    const bf16* kbase = qkv + (size_t)(b * 2048) * rs + 1024 + h * 64;
    const bf16* vbase = vt + (size_t)(bh * 64) * 2048;

    const int srow8  = lane >> 3;
    const int schunk = (lane & 7) ^ srow8;

    #define STAGE(J, BUF)                                                          \
        {   const int jj = (J);                                                    \
            _Pragma("unroll")                                                      \
            for (int i = 0; i < 2; i++) {                                          \
                int rr_ = wave * 16 + i * 8 + srow8;                               \
                const bf16* gk = kbase + (size_t)(jj * 64 + rr_) * rs + schunk * 8;\
                __builtin_amdgcn_global_load_lds(AS1C(gk),                         \
                    AS3(&Ks[BUF][(wave * 16 + i * 8) * 64]), 16, 0, 0);            \
                const bf16* gv = vbase + (size_t)rr_ * 2048 + jj * 64 + schunk * 8;\
                __builtin_amdgcn_global_load_lds(AS1C(gv),                         \
                    AS3(&Vs[BUF][(wave * 16 + i * 8) * 64]), 16, 0, 0);            \
            }                                                                      \
        }

    STAGE(0, 0)
    const int jmax = 2 * qt + 1;
    for (int j = 0; j <= jmax; j++) {
        __syncthreads();
        const int buf = j & 1;
        if (j < jmax) STAGE(j + 1, buf ^ 1)

        if (j * 64 > q0 + rowA + 31) continue;

        // s[mi][tc][rr] = P[k = j*64 + tc*16 + quad*4 + rr][q = rowA+mi*16+l15]
        f32x4 s[2][4];
        #pragma unroll
        for (int mi = 0; mi < 2; mi++)
            #pragma unroll
            for (int tc = 0; tc < 4; tc++) s[mi][tc] = (f32x4){0.f,0.f,0.f,0.f};
        #pragma unroll
        for (int kw = 0; kw < 2; kw++) {
            short8 kb[4];
            #pragma unroll
            for (int tc = 0; tc < 4; tc++)
                kb[tc] = *(const short8*)&Ks[buf][(tc * 16 + l15) * 64 +
                         (((kw * 4 + quad) ^ (l15 & 7)) * 8)];
            __builtin_amdgcn_s_setprio(1);
            #pragma unroll
            for (int mi = 0; mi < 2; mi++)
                #pragma unroll
                for (int tc = 0; tc < 4; tc++)
                    s[mi][tc] = __builtin_amdgcn_mfma_f32_16x16x32_bf16(
                        kb[tc], qa[mi][kw], s[mi][tc], 0, 0, 0);
            __builtin_amdgcn_s_setprio(0);
        }
        if (j * 64 + 63 > q0 + rowA) {
            #pragma unroll
            for (int mi = 0; mi < 2; mi++)
                #pragma unroll
                for (int tc = 0; tc < 4; tc++)
                    #pragma unroll
                    for (int rr = 0; rr < 4; rr++)
                        if (j * 64 + tc * 16 + quad * 4 + rr >
                            q0 + rowA + mi * 16 + l15)
                            s[mi][tc][rr] = -INFINITY;
        }
        #pragma unroll
        for (int mi = 0; mi < 2; mi++) {
            #pragma unroll
            for (int tc = 0; tc < 4; tc++)
                #pragma unroll
                for (int rr = 0; rr < 4; rr++)
                    s[mi][tc][rr] = __builtin_amdgcn_exp2f(s[mi][tc][rr]);
            #pragma unroll
            for (int tc = 0; tc < 4; tc++)
                lsum[mi] += (s[mi][tc][0] + s[mi][tc][1]) +
                            (s[mi][tc][2] + s[mi][tc][3]);
        }
        // Packed P store: rr runs along k -> one b64 per (mi,tc).
        #pragma unroll
        for (int mi = 0; mi < 2; mi++)
            #pragma unroll
            for (int tc = 0; tc < 4; tc++) {
                __align__(8) bf16 t4[4];
                #pragma unroll
                for (int rr = 0; rr < 4; rr++)
                    t4[rr] = __float2bfloat16(s[mi][tc][rr]);
                *(uint2*)&Ps[wave][mi][l15][tc * 16 + quad * 4] =
                    *(const uint2*)t4;
            }
        #pragma unroll
        for (int kw = 0; kw < 2; kw++) {
            short8 vb[4];
            #pragma unroll
            for (int nt = 0; nt < 4; nt++)
                vb[nt] = *(const short8*)&Vs[buf][(nt * 16 + l15) * 64 +
                         (((kw * 4 + quad) ^ (l15 & 7)) * 8)];
            short8 pa[2];
            #pragma unroll
            for (int mi = 0; mi < 2; mi++)
                pa[mi] = *(const short8*)&Ps[wave][mi][l15][kw * 32 + quad * 8];
            __builtin_amdgcn_s_setprio(1);
            #pragma unroll
            for (int mi = 0; mi < 2; mi++)
                #pragma unroll
                for (int nt = 0; nt < 4; nt++)
                    o[mi][nt] = __builtin_amdgcn_mfma_f32_16x16x32_bf16(
                        pa[mi], vb[nt], o[mi][nt], 0, 0, 0);
            __builtin_amdgcn_s_setprio(0);
        }
    }
    #undef STAGE

    // Row totals: sum partials across quads (lanes l15, +16, +32, +48),
    // then fetch each output row's total from lane (quad*4+rr).
    float inv[2][4];
    #pragma unroll
    for (int mi = 0; mi < 2; mi++) {
        float t = lsum[mi];
        t += __shfl_xor(t, 16);
        t += __shfl_xor(t, 32);
        #pragma unroll
        for (int rr = 0; rr < 4; rr++)
            inv[mi][rr] = 1.f / __shfl(t, quad * 4 + rr);
    }
    #pragma unroll
    for (int mi = 0; mi < 2; mi++)
        #pragma unroll
        for (int rr = 0; rr < 4; rr++) {
            int row = b * 2048 + q0 + rowA + mi * 16 + quad * 4 + rr;
            #pragma unroll
            for (int nt = 0; nt < 4; nt++) {
                int col = h * 64 + nt * 16 + l15;
                qkv[(size_t)row * rs + col] =
                    __float2bfloat16(o[mi][nt][rr] * inv[mi][rr]);
            }
        }
}

// ---------------------------------------------------------------------------
extern "C" void kernel_launch(void* const* d_in, const int* in_sizes, int n_in,
                              void* d_out, int out_size, void* d_ws, size_t ws_size,
                              hipStream_t stream)
{
    const float* x     = (const float*)d_in[0];  // [4,2048,1024] fp32
    const float* w_in  = (const float*)d_in[1];  // [3072,1024]   fp32
    const float* w_out = (const float*)d_in[2];  // [1024,1024]   fp32
    const float* b_out = (const float*)d_in[3];  // [1024]        fp32
    float* out = (float*)d_out;                  // [4,2048,1024] fp32

    // ws: qkv(Q|K) 33.5MB | vt 16.8MB | xb 16.8MB | wib 6.3MB | wob 2.1MB
    bf16* qkv = (bf16*)d_ws;                     // [8192, 2048]
    bf16* vt  = qkv + (size_t)8192 * 2048;       // [4096, 2048]
    bf16* xb  = vt  + (size_t)4096 * 2048;       // [8192, 1024]
    bf16* wib = xb  + (size_t)8192 * 1024;       // [3072, 1024]
    bf16* wob = wib + (size_t)3072 * 1024;       // [1024, 1024]

    // 0) one fused conversion launch
    cvt_all<<<(N4_X + N4_WI + N4_WO) / 256, 256, 0, stream>>>(
        x, xb, w_in, wib, w_out, wob);

    // 1) qkv = x @ w_in^T  (Q,K -> qkv stride 2048; V -> vt transposed)
    //    256x128 tile, 512 threads: staging+barrier cost per MFMA halves
    gemm_bt<256, true, false, bf16><<<dim3(8192 / 256, 3072 / 128), 512, 0, stream>>>(
        xb, 1024, wib, nullptr, qkv, 2048, vt, 8192, 3072, 1024);
    // 2) causal flash attention (output into Q columns of qkv)
    flash_attn<<<1024, 256, 0, stream>>>(qkv, vt);
    // 3) out = attn_out @ w_out^T + b_out  (TM=256: 256 blocks exact, 1/CU)
    gemm_bt<256, false, true, float><<<dim3(8192 / 256, 1024 / 128), 512, 0, stream>>>(
        qkv, 2048, wob, b_out, out, 1024, nullptr, 8192, 1024, 1024);
}